// Round 8
// baseline (352.130 us; speedup 1.0000x reference)
//
#include <hip/hip_runtime.h>
#include <math.h>

#define BATCH 4
#define CIN   1024
#define CB    256
#define HH    64
#define WW    64
#define PP    4096          // HH*WW
#define EPSV  1e-5f

using shortx8 = __attribute__((ext_vector_type(8))) short;
using floatx4 = __attribute__((ext_vector_type(4))) float;

static __device__ inline unsigned short f2bf(float f) {
    unsigned int u = __float_as_uint(f);
    u += 0x7fffu + ((u >> 16) & 1u);      // RNE
    return (unsigned short)(u >> 16);
}
static __device__ inline float bf2f(unsigned short s) {
    return __uint_as_float(((unsigned int)s) << 16);
}
static __device__ inline float bflo(unsigned int u) {
    return __uint_as_float(u << 16);
}
static __device__ inline float bfhi(unsigned int u) {
    return __uint_as_float(u & 0xffff0000u);
}

// ---------------------------------------------------------------------------
// bf16 MFMA GEMM (conv1 / conv3) + fused GN-stats partial accumulation.
// R18: each block reduces its output tile's sum/sumsq per channel-group
// (butterfly over l15 -> LDS bins -> 1 global atomicAdd per group) so the
// separate gn_stats_part full-tensor read dies. gshift = log2(Cpg).
// ---------------------------------------------------------------------------
__global__ __launch_bounds__(256)
void gemm_bf16(const unsigned short* __restrict__ A,
               const unsigned short* __restrict__ BTg,
               float* __restrict__ Cg, int M, int N, int K,
               float* __restrict__ pS, float* __restrict__ pSS, int gshift) {
    const int b = blockIdx.z;
    const unsigned short* BT = BTg + (size_t)b * N * K;
    float* C = Cg + (size_t)b * M * N;
    const int m0 = blockIdx.y * 128;
    const int n0 = blockIdx.x * 128;
    const int tid = threadIdx.x;
    const int lane = tid & 63;
    const int wid = tid >> 6;
    const int l15 = lane & 15;
    const int quad = lane >> 4;

    __shared__ __align__(16) unsigned short As[128 * 40];
    __shared__ __align__(16) unsigned short Bs[128 * 40];
    __shared__ float sgs[32], sgss[32];
    if (tid < 32) { sgs[tid] = 0.f; sgss[tid] = 0.f; }

    floatx4 acc[2][8];
#pragma unroll
    for (int i = 0; i < 2; i++)
#pragma unroll
        for (int j = 0; j < 8; j++) acc[i][j] = (floatx4){0.f, 0.f, 0.f, 0.f};

    const int row = tid >> 1;
    const int half = tid & 1;

    for (int k0 = 0; k0 < K; k0 += 32) {
        const unsigned short* ga = A + (size_t)(m0 + row) * K + k0 + half * 16;
        const unsigned short* gb = BT + (size_t)(n0 + row) * K + k0 + half * 16;
        float4 a0 = *(const float4*)ga;
        float4 a1 = *(const float4*)(ga + 8);
        float4 b0 = *(const float4*)gb;
        float4 b1 = *(const float4*)(gb + 8);
        __syncthreads();
        *(float4*)((char*)As + row * 80 + half * 32) = a0;
        *(float4*)((char*)As + row * 80 + half * 32 + 16) = a1;
        *(float4*)((char*)Bs + row * 80 + half * 32) = b0;
        *(float4*)((char*)Bs + row * 80 + half * 32 + 16) = b1;
        __syncthreads();
        shortx8 af[2], bf[8];
#pragma unroll
        for (int i = 0; i < 2; i++)
            af[i] = *(const shortx8*)((const char*)As +
                    (wid * 32 + 16 * i + l15) * 80 + quad * 16);
#pragma unroll
        for (int j = 0; j < 8; j++)
            bf[j] = *(const shortx8*)((const char*)Bs +
                    (16 * j + l15) * 80 + quad * 16);
#pragma unroll
        for (int i = 0; i < 2; i++)
#pragma unroll
            for (int j = 0; j < 8; j++)
                acc[i][j] = __builtin_amdgcn_mfma_f32_16x16x32_bf16(
                    af[i], bf[j], acc[i][j], 0, 0, 0);
    }

#pragma unroll
    for (int i = 0; i < 2; i++) {
#pragma unroll
        for (int r = 0; r < 4; r++) {
            int m = m0 + wid * 32 + 16 * i + quad * 4 + r;
            float* dst = C + (size_t)m * N + n0 + l15;
            float s = 0.f, ss = 0.f;
#pragma unroll
            for (int j = 0; j < 8; j++) {
                float v = acc[i][j][r];
                dst[16 * j] = v;
                s += v; ss += v * v;
            }
#pragma unroll
            for (int off = 1; off < 16; off <<= 1) {
                s  += __shfl_xor(s, off, 64);
                ss += __shfl_xor(ss, off, 64);
            }
            if (l15 == 0) {
                int g = (m >> gshift) & 31;
                atomicAdd(&sgs[g], s);
                atomicAdd(&sgss[g], ss);
            }
        }
    }
    __syncthreads();
    if (tid < 32) {
        atomicAdd(&pS[b * 32 + tid], sgs[tid]);
        atomicAdd(&pSS[b * 32 + tid], sgss[tid]);
    }
}

// ---------------------------------------------------------------------------
// Tiled transpose + fp32->bf16: src [b][C][P] -> dst [b][P][C]
// ---------------------------------------------------------------------------
__global__ __launch_bounds__(256)
void transp_bf16(const float* __restrict__ src, unsigned short* __restrict__ dst,
                 int C, int P) {
    const int p0 = blockIdx.x * 64;
    const int c0 = blockIdx.y * 64;
    const int b = blockIdx.z;
    __shared__ unsigned short t[64][72];
    const float* s = src + ((size_t)b * C + c0) * P + p0;
    for (int e = threadIdx.x; e < 4096; e += 256) {
        int r = e >> 6, col = e & 63;
        t[r][col] = f2bf(s[(size_t)r * P + col]);
    }
    __syncthreads();
    unsigned short* d = dst + ((size_t)b * P + p0) * C + c0;
    for (int u = threadIdx.x; u < 512; u += 256) {
        int pr = u >> 3, c8 = (u & 7) * 8;
        ushort4 v0, v1;
        v0.x = t[c8 + 0][pr]; v0.y = t[c8 + 1][pr];
        v0.z = t[c8 + 2][pr]; v0.w = t[c8 + 3][pr];
        v1.x = t[c8 + 4][pr]; v1.y = t[c8 + 5][pr];
        v1.z = t[c8 + 6][pr]; v1.w = t[c8 + 7][pr];
        *(ushort4*)&d[(size_t)pr * C + c8] = v0;
        *(ushort4*)&d[(size_t)pr * C + c8 + 4] = v1;
    }
}

// ---------------------------------------------------------------------------
// GN apply + ReLU + transpose-convert: src fp32 [b][256][P] -> bf16 [b][P][256]
// (used for gn1 -> bfAT and gn2 -> out2bT)
// ---------------------------------------------------------------------------
__global__ __launch_bounds__(256)
void gn2t(const float* __restrict__ src, const float2* __restrict__ st,
          const float* __restrict__ sc, const float* __restrict__ bi,
          unsigned short* __restrict__ dst) {
    const int p0 = blockIdx.x * 64;
    const int c0 = blockIdx.y * 64;
    const int b = blockIdx.z;
    __shared__ unsigned short t[64][72];
    const float* s = src + ((size_t)b * CB + c0) * PP + p0;
    for (int e = threadIdx.x; e < 4096; e += 256) {
        int r = e >> 6, col = e & 63;
        int c = c0 + r;
        float2 m = st[b * 32 + (c >> 3)];       // Cpg = 8
        float a = m.y * sc[c];
        float bb = bi[c] - m.x * a;
        t[r][col] = f2bf(fmaxf(s[(size_t)r * PP + col] * a + bb, 0.f));
    }
    __syncthreads();
    unsigned short* d = dst + ((size_t)b * PP + p0) * CB + c0;
    for (int u = threadIdx.x; u < 512; u += 256) {
        int pr = u >> 3, c8 = (u & 7) * 8;
        ushort4 v0, v1;
        v0.x = t[c8 + 0][pr]; v0.y = t[c8 + 1][pr];
        v0.z = t[c8 + 2][pr]; v0.w = t[c8 + 3][pr];
        v1.x = t[c8 + 4][pr]; v1.y = t[c8 + 5][pr];
        v1.z = t[c8 + 6][pr]; v1.w = t[c8 + 7][pr];
        *(ushort4*)&d[(size_t)pr * CB + c8] = v0;
        *(ushort4*)&d[(size_t)pr * CB + c8 + 4] = v1;
    }
}

// ---------------------------------------------------------------------------
__global__ __launch_bounds__(256)
void cvt_bf16(const float* __restrict__ s, unsigned short* __restrict__ d, int n) {
    int i = blockIdx.x * 256 + threadIdx.x;
    if (i < n) d[i] = f2bf(s[i]);
}

// ---------------------------------------------------------------------------
// Finalize: stats from accumulated partials (one float pair per (b,group)).
// ---------------------------------------------------------------------------
__global__ __launch_bounds__(128)
void gn_stats_fin(const float* __restrict__ pS, const float* __restrict__ pSS,
                  float2* __restrict__ stats, int cnt) {
    int bg = threadIdx.x;           // 128 (b,g) pairs
    float S = pS[bg], SS = pSS[bg];
    float mean = S / (float)cnt;
    float var = SS / (float)cnt - mean * mean;
    stats[bg] = make_float2(mean, rsqrtf(var + EPSV));
}

// ---------------------------------------------------------------------------
// w_off fp32 [27][256][9] -> bf16 wobf [32][2304], layout m*2304 + tap*256 + c,
// rows 27..31 zero (M padded to 32 for MFMA).
// ---------------------------------------------------------------------------
__global__ __launch_bounds__(256)
void woff_conv(const float* __restrict__ w_off, unsigned short* __restrict__ wobf) {
    int t = blockIdx.x * 256 + threadIdx.x;
    if (t >= 32 * 2304) return;
    int m = t / 2304;
    int r = t - m * 2304;
    int tap = r >> 8, c = r & 255;
    float v = (m < 27) ? w_off[((size_t)m * 256 + c) * 9 + tap] : 0.f;
    wobf[t] = f2bf(v);
}

// ---------------------------------------------------------------------------
// Offset conv on MFMA (R17, proven: conv_off 68 -> <15 us).
// ---------------------------------------------------------------------------
__global__ __launch_bounds__(256)
void conv_off_mfma(const unsigned short* __restrict__ bfAT,
                   const unsigned short* __restrict__ wobf,
                   const float* __restrict__ boff,
                   float* __restrict__ om) {
    const int blk = blockIdx.x;          // 512 blocks
    const int xcd = blk & 7;
    const int b = xcd >> 1;              // batch per XCD-pair
    const int tile = ((blk >> 3) << 1) | (xcd & 1);   // 0..127
    const int p0 = tile * 32;
    const int tid = threadIdx.x;
    const int lane = tid & 63;
    const int wid = tid >> 6;            // 0..3
    const int l15 = lane & 15;
    const int quad = lane >> 4;
    const int mh = (wid >> 1) << 4;      // m-half: 0 or 16
    const int ph = (wid & 1) << 4;       // px-half: 0 or 16

    __shared__ __align__(16) unsigned short Bs[8 * 1288];   // 20.6 KB

    const int y0r = p0 >> 6;             // image row (constant per tile)
    const int x0 = p0 & 63;              // 0 or 32
    const unsigned short* xb = bfAT + ((size_t)b << 20);
    const unsigned short* arow = wobf + (size_t)(mh + l15) * 2304 + quad * 8;

    floatx4 acc = (floatx4){0.f, 0.f, 0.f, 0.f};

    for (int tap = 0; tap < 9; ++tap) {
        const int dy = tap / 3 - 1, dx = tap % 3 - 1;
        const int yy = y0r + dy;
        const bool rowok = (yy >= 0 && yy < 64);
        __syncthreads();
        for (int e = tid; e < 1024; e += 256) {
            int px = e >> 5, ck = e & 31;
            int xx = x0 + px + dx;
            uint4 v = make_uint4(0u, 0u, 0u, 0u);
            if (rowok && xx >= 0 && xx < 64) {
                int srow = (yy << 6) + xx;
                v = *(const uint4*)(xb + ((size_t)srow << 8) + ck * 8);
            }
            *(uint4*)((char*)Bs + (ck >> 2) * 2576 + px * 80 + (ck & 3) * 16) = v;
        }
        __syncthreads();
        const unsigned short* at = arow + tap * 256;
#pragma unroll
        for (int cc = 0; cc < 8; ++cc) {
            shortx8 af = *(const shortx8*)(at + cc * 32);
            shortx8 bf = *(const shortx8*)((const char*)Bs + cc * 2576 +
                         (ph + l15) * 80 + quad * 16);
            acc = __builtin_amdgcn_mfma_f32_16x16x32_bf16(af, bf, acc, 0, 0, 0);
        }
    }

    // epilogue: col = l15 (pixel), row = quad*4 + r (within m-half); + bias
#pragma unroll
    for (int r = 0; r < 4; ++r) {
        int m = mh + quad * 4 + r;
        if (m < 27)
            om[((size_t)b * 27 + m) * PP + p0 + ph + l15] = acc[r] + boff[m];
    }
}

// ---------------------------------------------------------------------------
// Deformable einsum, bf16 MFMA. R18: DIRECT A-FRAGMENT LOADS — wave w reads
// only rows mbase..mbase+31 of the A panel, so the As LDS staging had zero
// cross-wave reuse: 40KB write + 32KB read per segment of pure overhead
// (~half the kernel's LDS traffic). A fragments now load straight from the
// L2-resident w2bf with the MFMA lane layout (same 64B lines as before),
// depth-1 prefetched alongside the corners. B staging (real cross-wave
// reuse: all waves read all 64 px) and both barriers unchanged.
// Also: fused GN2-stats partial accumulation in the epilogue.
// ---------------------------------------------------------------------------
__global__ __launch_bounds__(512, 2)
void gemm2_mfma(const unsigned short* __restrict__ bfAT,
                const unsigned short* __restrict__ w2bf,
                const float* __restrict__ om, float* __restrict__ out2,
                float* __restrict__ pS, float* __restrict__ pSS) {
    const int blk = blockIdx.x;        // 256 blocks
    const int xcd = blk & 7;
    const int b = xcd >> 1;                          // batch per XCD-pair
    const int p0 = (((blk >> 3) << 1) | (xcd & 1)) * 64;
    const int tid = threadIdx.x;
    const int lane = tid & 63;
    const int wid = tid >> 6;          // 0..7
    const int l15 = lane & 15;
    const int quad = lane >> 4;        // 0..3

    __shared__ __align__(16) unsigned short Bs0[64 * 40];    // 5 KB
    __shared__ __align__(16) unsigned short Bs1[64 * 40];    // 5 KB
    __shared__ float sw0[576], sw1[576], sw2[576], sw3[576]; // SoA tables
    __shared__ int   si0[576], si1[576];                     // row indices
    __shared__ float sgs[32], sgss[32];
    if (tid < 32) { sgs[tid] = 0.f; sgss[tid] = 0.f; }

    // sampling tables, 9 taps x 64 pixels
    const float* ob = om + (size_t)b * 27 * PP;
    for (int e = tid; e < 576; e += 512) {
        int k = e >> 6, p = e & 63;
        int pg = p0 + p;
        float offx = ob[(size_t)k * PP + pg];
        float offy = ob[(size_t)(9 + k) * PP + pg];
        float ms = 1.f / (1.f + expf(-ob[(size_t)(18 + k) * PP + pg]));
        int y = pg >> 6, x = pg & 63;
        float py = (float)(y + k / 3 - 1) + offy;
        float px = (float)(x + (k % 3) - 1) + offx;
        float y0f = floorf(py), x0f = floorf(px);
        float wy1 = py - y0f, wx1 = px - x0f;
        int iy0 = (int)y0f, ix0 = (int)x0f;
        int iy1 = iy0 + 1;
        float wy0v = (iy0 >= 0 && iy0 < 64) ? (1.f - wy1) * ms : 0.f;
        float wy1v = (iy1 >= 0 && iy1 < 64) ? wy1 * ms : 0.f;
        int cy0 = min(max(iy0, 0), 63), cy1 = min(max(iy1, 0), 63);
        float xa, xb; int q;
        if (ix0 >= 0 && ix0 <= 62)      { q = ix0; xa = 1.f - wx1; xb = wx1;       }
        else if (ix0 == -1)             { q = 0;   xa = wx1;       xb = 0.f;       }
        else if (ix0 == 63)             { q = 62;  xa = 0.f;       xb = 1.f - wx1; }
        else                            { q = 0;   xa = 0.f;       xb = 0.f;       }
        sw0[e] = wy0v * xa;
        sw1[e] = wy0v * xb;
        sw2[e] = wy1v * xa;
        sw3[e] = wy1v * xb;
        si0[e] = (cy0 << 6) + q;
        si1[e] = (cy1 << 6) + q;
    }

    floatx4 acc[2][4];
#pragma unroll
    for (int i = 0; i < 2; i++)
#pragma unroll
        for (int j = 0; j < 4; j++) acc[i][j] = (floatx4){0.f, 0.f, 0.f, 0.f};

    const int cq = tid & 7;            // channel octet (8 contiguous channels)
    const int bp = tid >> 3;           // pixel within tile 0..63
    const unsigned short* xbase = bfAT + (((size_t)b) << 20);   // b*PP*256
    const unsigned short* gbq = xbase + cq * 8;
    const int mbase = wid * 32;
    // A fragment base: row (mbase+16i+l15), k-offset tap*256+cc2*64+ks*32+quad*8
    const unsigned short* afb = w2bf + (size_t)(mbase + l15) * 2304 + quad * 8;

    __syncthreads();   // tables ready (also covers sgs zero-init)

    // ---- prologue: prefetch segment 0 (cc2=0, tap=0) ----
    shortx8 afc[2][2];
    uint4 v00, v01, v10, v11;
    float w0, w1, w2v, w3v;
    {
#pragma unroll
        for (int ks = 0; ks < 2; ks++)
#pragma unroll
            for (int i = 0; i < 2; i++)
                afc[ks][i] = *(const shortx8*)(afb + (size_t)i * 36864 + ks * 32);
        int tix = bp;
        w0 = sw0[tix]; w1 = sw1[tix]; w2v = sw2[tix]; w3v = sw3[tix];
        int r0 = si0[tix], r1 = si1[tix];
        v00 = *(const uint4*)(gbq + ((size_t)r0 << 8));
        v01 = *(const uint4*)(gbq + ((size_t)(r0 + 1) << 8));
        v10 = *(const uint4*)(gbq + ((size_t)r1 << 8));
        v11 = *(const uint4*)(gbq + ((size_t)(r1 + 1) << 8));
    }

    int tap = 0, cc2 = 0;
    for (int seg = 0; seg < 36; ++seg) {
        // ---- interp current corners + stage B ----
        float f0 = w0 * bflo(v00.x) + w1 * bflo(v01.x)
                 + w2v * bflo(v10.x) + w3v * bflo(v11.x);
        float f1 = w0 * bfhi(v00.x) + w1 * bfhi(v01.x)
                 + w2v * bfhi(v10.x) + w3v * bfhi(v11.x);
        float f2 = w0 * bflo(v00.y) + w1 * bflo(v01.y)
                 + w2v * bflo(v10.y) + w3v * bflo(v11.y);
        float f3 = w0 * bfhi(v00.y) + w1 * bfhi(v01.y)
                 + w2v * bfhi(v10.y) + w3v * bfhi(v11.y);
        float f4 = w0 * bflo(v00.z) + w1 * bflo(v01.z)
                 + w2v * bflo(v10.z) + w3v * bflo(v11.z);
        float f5 = w0 * bfhi(v00.z) + w1 * bfhi(v01.z)
                 + w2v * bfhi(v10.z) + w3v * bfhi(v11.z);
        float f6 = w0 * bflo(v00.w) + w1 * bflo(v01.w)
                 + w2v * bflo(v10.w) + w3v * bflo(v11.w);
        float f7 = w0 * bfhi(v00.w) + w1 * bfhi(v01.w)
                 + w2v * bfhi(v10.w) + w3v * bfhi(v11.w);
        uint4 bw;
        bw.x = (unsigned int)f2bf(f0) | ((unsigned int)f2bf(f1) << 16);
        bw.y = (unsigned int)f2bf(f2) | ((unsigned int)f2bf(f3) << 16);
        bw.z = (unsigned int)f2bf(f4) | ((unsigned int)f2bf(f5) << 16);
        bw.w = (unsigned int)f2bf(f6) | ((unsigned int)f2bf(f7) << 16);
        unsigned short* bdst = (cq & 4) ? Bs1 : Bs0;
        *(uint4*)((char*)bdst + bp * 80 + (cq & 3) * 16) = bw;
        __syncthreads();

        // ---- prefetch next segment (A frags + corners) ----
        int ntap = tap + 1, ncc2 = cc2;
        if (ntap == 9) { ntap = 0; ncc2 = (cc2 + 1) & 3; }
        shortx8 afn[2][2];
        {
            const unsigned short* ab = afb + ntap * 256 + ncc2 * 64;
#pragma unroll
            for (int ks = 0; ks < 2; ks++)
#pragma unroll
                for (int i = 0; i < 2; i++)
                    afn[ks][i] = *(const shortx8*)(ab + (size_t)i * 36864 + ks * 32);
            int tix = ntap * 64 + bp;
            int r0 = si0[tix], r1 = si1[tix];
            const unsigned short* gb = gbq + ncc2 * 64;
            v00 = *(const uint4*)(gb + ((size_t)r0 << 8));
            v01 = *(const uint4*)(gb + ((size_t)(r0 + 1) << 8));
            v10 = *(const uint4*)(gb + ((size_t)r1 << 8));
            v11 = *(const uint4*)(gb + ((size_t)(r1 + 1) << 8));
            w0 = sw0[tix]; w1 = sw1[tix]; w2v = sw2[tix]; w3v = sw3[tix];
        }

        // ---- MFMA: register A frags x LDS B ----
        shortx8 bfr[2][4];
#pragma unroll
        for (int j = 0; j < 4; j++) {
            bfr[0][j] = *(const shortx8*)((const char*)Bs0 +
                        (16 * j + l15) * 80 + quad * 16);
            bfr[1][j] = *(const shortx8*)((const char*)Bs1 +
                        (16 * j + l15) * 80 + quad * 16);
        }
#pragma unroll
        for (int ks = 0; ks < 2; ks++)
#pragma unroll
            for (int i = 0; i < 2; i++)
#pragma unroll
                for (int j = 0; j < 4; j++)
                    acc[i][j] = __builtin_amdgcn_mfma_f32_16x16x32_bf16(
                        afc[ks][i], bfr[ks][j], acc[i][j], 0, 0, 0);
        __syncthreads();
#pragma unroll
        for (int ks = 0; ks < 2; ks++)
#pragma unroll
            for (int i = 0; i < 2; i++)
                afc[ks][i] = afn[ks][i];
        tap = ntap; cc2 = ncc2;
    }

    // epilogue: write C + fused GN2-stats partials
    const size_t chbase = ((size_t)b * CB) << 12;
#pragma unroll
    for (int i = 0; i < 2; i++) {
#pragma unroll
        for (int r = 0; r < 4; r++) {
            int row = mbase + 16 * i + quad * 4 + r;
            float* dst = out2 + chbase + ((size_t)row << 12) + p0 + l15;
            float s = 0.f, ss = 0.f;
#pragma unroll
            for (int j = 0; j < 4; j++) {
                float v = acc[i][j][r];
                dst[16 * j] = v;
                s += v; ss += v * v;
            }
#pragma unroll
            for (int off = 1; off < 16; off <<= 1) {
                s  += __shfl_xor(s, off, 64);
                ss += __shfl_xor(ss, off, 64);
            }
            if (l15 == 0) {
                int g = row >> 3;          // Cpg = 8
                atomicAdd(&sgs[g], s);
                atomicAdd(&sgss[g], ss);
            }
        }
    }
    __syncthreads();
    if (tid < 32) {
        atomicAdd(&pS[b * 32 + tid], sgs[tid]);
        atomicAdd(&pSS[b * 32 + tid], sgss[tid]);
    }
}

// ---------------------------------------------------------------------------
// w2 fp32 [o][c][tap] -> bf16, K reordered: w2bf[o][tap*256 + c]
// ---------------------------------------------------------------------------
__global__ __launch_bounds__(256)
void w2conv(const float* __restrict__ w2, unsigned short* __restrict__ w2bf) {
    int t = blockIdx.x * 256 + threadIdx.x;
    if (t >= 256 * 2304) return;
    int o = t / 2304;
    int r = t - o * 2304;
    int tap = r >> 8, c = r & 255;
    w2bf[t] = f2bf(w2[((size_t)o * 256 + c) * 9 + tap]);
}

// ---------------------------------------------------------------------------
// Final: relu(gn3(d_out)*sc+bi + x) in place.
// ---------------------------------------------------------------------------
__global__ __launch_bounds__(256)
void final_k(float* __restrict__ dout, const float* __restrict__ x,
             const float2* __restrict__ stats, const float* __restrict__ sc,
             const float* __restrict__ bi) {
    long i = (long)blockIdx.x * 256 + threadIdx.x;
    long total4 = ((long)BATCH * CIN * PP) >> 2;
    if (i >= total4) return;
    long e = i << 2;
    int c = (int)((e >> 12) & 1023);
    int b = (int)(e >> 22);
    float2 st = stats[b * 32 + (c >> 5)];
    float a = st.y * sc[c];
    float bb = bi[c] - st.x * a;
    float4 v = ((float4*)dout)[i];
    float4 xv = ((const float4*)x)[i];
    v.x = fmaxf(v.x * a + bb + xv.x, 0.f);
    v.y = fmaxf(v.y * a + bb + xv.y, 0.f);
    v.z = fmaxf(v.z * a + bb + xv.z, 0.f);
    v.w = fmaxf(v.w * a + bb + xv.w, 0.f);
    ((float4*)dout)[i] = v;
}

// ---------------------------------------------------------------------------
// Workspace: bfAT at ws+6422528; wobf at ws+9256960; stats partials (pbuf,
// 768 floats, memset to 0) after st3.
// ---------------------------------------------------------------------------
extern "C" void kernel_launch(void* const* d_in, const int* in_sizes, int n_in,
                              void* d_out, int out_size, void* d_ws, size_t ws_size,
                              hipStream_t stream) {
    const float* x   = (const float*)d_in[0];
    const float* w1  = (const float*)d_in[1];
    const float* g1s = (const float*)d_in[2];
    const float* g1b = (const float*)d_in[3];
    const float* wof = (const float*)d_in[4];
    const float* bof = (const float*)d_in[5];
    const float* w2  = (const float*)d_in[6];
    const float* g2s = (const float*)d_in[7];
    const float* g2b = (const float*)d_in[8];
    const float* w3  = (const float*)d_in[9];
    const float* g3s = (const float*)d_in[10];
    const float* g3b = (const float*)d_in[11];
    float* out = (float*)d_out;

    float* ws = (float*)d_ws;
    unsigned short* w1bf   = (unsigned short*)(ws + 0);
    float*          out1r  = ws + 131072;               // conv1 raw out
    float*          out2   = ws + 131072;               // aliases out1r (dead)
    unsigned short* xbfT   = (unsigned short*)(ws + 4325376);
    unsigned short* bfAT   = (unsigned short*)(ws + 6422528);  // pixel-major GN1 out
    float*          om     = ws + 8519680;
    unsigned short* w2bf   = (unsigned short*)(ws + 8962048);
    unsigned short* wobf   = (unsigned short*)(ws + 9256960);  // offset-conv W bf16
    unsigned short* out2bT = (unsigned short*)(ws + 4325376);  // reuses xbfT region
    unsigned short* w3bf   = (unsigned short*)(ws + 11354112);
    float2* st1  = (float2*)(ws + 11485184);
    float2* st2  = st1 + 128;
    float2* st3  = st2 + 128;
    float*  pbuf = ws + 11485184 + 768;   // 768 floats: 3 stages x (S[128],SS[128])
    float*  p1S = pbuf,       *p1SS = pbuf + 128;
    float*  p2S = pbuf + 256, *p2SS = pbuf + 384;
    float*  p3S = pbuf + 512, *p3SS = pbuf + 640;

    hipMemsetAsync(pbuf, 0, 768 * sizeof(float), stream);

    // x [b][1024][4096] -> xbfT [b][4096][1024] bf16
    transp_bf16<<<dim3(64, 16, 4), 256, 0, stream>>>(x, xbfT, 1024, 4096);
    cvt_bf16<<<1024, 256, 0, stream>>>(w1, w1bf, 262144);
    // conv1 (+fused GN1 stats partials): out1r = w1bf @ xbfT
    gemm_bf16<<<dim3(32, 2, 4), 256, 0, stream>>>(w1bf, xbfT, out1r, 256, 4096, 1024,
                                                  p1S, p1SS, 3);
    gn_stats_fin<<<1, 128, 0, stream>>>(p1S, p1SS, st1, 8 * PP);
    // GN1 apply + ReLU -> bfAT (pixel-major)
    gn2t<<<dim3(64, 4, 4), 256, 0, stream>>>(out1r, st1, g1s, g1b, bfAT);
    // offset conv on MFMA (reads bfAT; bias fused)
    woff_conv<<<288, 256, 0, stream>>>(wof, wobf);
    conv_off_mfma<<<512, 256, 0, stream>>>(bfAT, wobf, bof, om);
    // weight conversions
    w2conv<<<2304, 256, 0, stream>>>(w2, w2bf);
    cvt_bf16<<<1024, 256, 0, stream>>>(w3, w3bf, 262144);
    // deformable einsum (+fused GN2 stats partials) -> out2
    gemm2_mfma<<<dim3(256, 1, 1), 512, 0, stream>>>(bfAT, w2bf, om, out2, p2S, p2SS);
    gn_stats_fin<<<1, 128, 0, stream>>>(p2S, p2SS, st2, 8 * PP);
    gn2t<<<dim3(64, 4, 4), 256, 0, stream>>>(out2, st2, g2s, g2b, out2bT);
    // conv3 (+fused GN3 stats partials): out = w3bf @ out2bT
    gemm_bf16<<<dim3(32, 8, 4), 256, 0, stream>>>(w3bf, out2bT, out, 1024, 4096, 256,
                                                  p3S, p3SS, 5);
    gn_stats_fin<<<1, 128, 0, stream>>>(p3S, p3SS, st3, 32 * PP);
    final_k<<<16384, 256, 0, stream>>>(out, x, st3, g3s, g3b);
}

// Round 9
// 338.103 us; speedup vs baseline: 1.0415x; 1.0415x over previous
//
#include <hip/hip_runtime.h>
#include <math.h>

#define BATCH 4
#define CIN   1024
#define CB    256
#define HH    64
#define WW    64
#define PP    4096          // HH*WW
#define EPSV  1e-5f

using shortx8 = __attribute__((ext_vector_type(8))) short;
using floatx4 = __attribute__((ext_vector_type(4))) float;

static __device__ inline unsigned short f2bf(float f) {
    unsigned int u = __float_as_uint(f);
    u += 0x7fffu + ((u >> 16) & 1u);      // RNE
    return (unsigned short)(u >> 16);
}
static __device__ inline float bf2f(unsigned short s) {
    return __uint_as_float(((unsigned int)s) << 16);
}
static __device__ inline float bflo(unsigned int u) {
    return __uint_as_float(u << 16);
}
static __device__ inline float bfhi(unsigned int u) {
    return __uint_as_float(u & 0xffff0000u);
}

// ---------------------------------------------------------------------------
// bf16 MFMA GEMM (conv1 / conv3) + fused GN-stats partial accumulation
// (R18, proven: kills the separate full-tensor stats read). gshift=log2(Cpg).
// ---------------------------------------------------------------------------
__global__ __launch_bounds__(256)
void gemm_bf16(const unsigned short* __restrict__ A,
               const unsigned short* __restrict__ BTg,
               float* __restrict__ Cg, int M, int N, int K,
               float* __restrict__ pS, float* __restrict__ pSS, int gshift) {
    const int b = blockIdx.z;
    const unsigned short* BT = BTg + (size_t)b * N * K;
    float* C = Cg + (size_t)b * M * N;
    const int m0 = blockIdx.y * 128;
    const int n0 = blockIdx.x * 128;
    const int tid = threadIdx.x;
    const int lane = tid & 63;
    const int wid = tid >> 6;
    const int l15 = lane & 15;
    const int quad = lane >> 4;

    __shared__ __align__(16) unsigned short As[128 * 40];
    __shared__ __align__(16) unsigned short Bs[128 * 40];
    __shared__ float sgs[32], sgss[32];
    if (tid < 32) { sgs[tid] = 0.f; sgss[tid] = 0.f; }

    floatx4 acc[2][8];
#pragma unroll
    for (int i = 0; i < 2; i++)
#pragma unroll
        for (int j = 0; j < 8; j++) acc[i][j] = (floatx4){0.f, 0.f, 0.f, 0.f};

    const int row = tid >> 1;
    const int half = tid & 1;

    for (int k0 = 0; k0 < K; k0 += 32) {
        const unsigned short* ga = A + (size_t)(m0 + row) * K + k0 + half * 16;
        const unsigned short* gb = BT + (size_t)(n0 + row) * K + k0 + half * 16;
        float4 a0 = *(const float4*)ga;
        float4 a1 = *(const float4*)(ga + 8);
        float4 b0 = *(const float4*)gb;
        float4 b1 = *(const float4*)(gb + 8);
        __syncthreads();
        *(float4*)((char*)As + row * 80 + half * 32) = a0;
        *(float4*)((char*)As + row * 80 + half * 32 + 16) = a1;
        *(float4*)((char*)Bs + row * 80 + half * 32) = b0;
        *(float4*)((char*)Bs + row * 80 + half * 32 + 16) = b1;
        __syncthreads();
        shortx8 af[2], bf[8];
#pragma unroll
        for (int i = 0; i < 2; i++)
            af[i] = *(const shortx8*)((const char*)As +
                    (wid * 32 + 16 * i + l15) * 80 + quad * 16);
#pragma unroll
        for (int j = 0; j < 8; j++)
            bf[j] = *(const shortx8*)((const char*)Bs +
                    (16 * j + l15) * 80 + quad * 16);
#pragma unroll
        for (int i = 0; i < 2; i++)
#pragma unroll
            for (int j = 0; j < 8; j++)
                acc[i][j] = __builtin_amdgcn_mfma_f32_16x16x32_bf16(
                    af[i], bf[j], acc[i][j], 0, 0, 0);
    }

#pragma unroll
    for (int i = 0; i < 2; i++) {
#pragma unroll
        for (int r = 0; r < 4; r++) {
            int m = m0 + wid * 32 + 16 * i + quad * 4 + r;
            float* dst = C + (size_t)m * N + n0 + l15;
            float s = 0.f, ss = 0.f;
#pragma unroll
            for (int j = 0; j < 8; j++) {
                float v = acc[i][j][r];
                dst[16 * j] = v;
                s += v; ss += v * v;
            }
#pragma unroll
            for (int off = 1; off < 16; off <<= 1) {
                s  += __shfl_xor(s, off, 64);
                ss += __shfl_xor(ss, off, 64);
            }
            if (l15 == 0) {
                int g = (m >> gshift) & 31;
                atomicAdd(&sgs[g], s);
                atomicAdd(&sgss[g], ss);
            }
        }
    }
    __syncthreads();
    if (tid < 32) {
        atomicAdd(&pS[b * 32 + tid], sgs[tid]);
        atomicAdd(&pSS[b * 32 + tid], sgss[tid]);
    }
}

// ---------------------------------------------------------------------------
// Tiled transpose + fp32->bf16: src [b][C][P] -> dst [b][P][C]
// ---------------------------------------------------------------------------
__global__ __launch_bounds__(256)
void transp_bf16(const float* __restrict__ src, unsigned short* __restrict__ dst,
                 int C, int P) {
    const int p0 = blockIdx.x * 64;
    const int c0 = blockIdx.y * 64;
    const int b = blockIdx.z;
    __shared__ unsigned short t[64][72];
    const float* s = src + ((size_t)b * C + c0) * P + p0;
    for (int e = threadIdx.x; e < 4096; e += 256) {
        int r = e >> 6, col = e & 63;
        t[r][col] = f2bf(s[(size_t)r * P + col]);
    }
    __syncthreads();
    unsigned short* d = dst + ((size_t)b * P + p0) * C + c0;
    for (int u = threadIdx.x; u < 512; u += 256) {
        int pr = u >> 3, c8 = (u & 7) * 8;
        ushort4 v0, v1;
        v0.x = t[c8 + 0][pr]; v0.y = t[c8 + 1][pr];
        v0.z = t[c8 + 2][pr]; v0.w = t[c8 + 3][pr];
        v1.x = t[c8 + 4][pr]; v1.y = t[c8 + 5][pr];
        v1.z = t[c8 + 6][pr]; v1.w = t[c8 + 7][pr];
        *(ushort4*)&d[(size_t)pr * C + c8] = v0;
        *(ushort4*)&d[(size_t)pr * C + c8 + 4] = v1;
    }
}

// ---------------------------------------------------------------------------
// GN apply + ReLU + transpose-convert: src fp32 [b][256][P] -> bf16 [b][P][256]
// ---------------------------------------------------------------------------
__global__ __launch_bounds__(256)
void gn2t(const float* __restrict__ src, const float2* __restrict__ st,
          const float* __restrict__ sc, const float* __restrict__ bi,
          unsigned short* __restrict__ dst) {
    const int p0 = blockIdx.x * 64;
    const int c0 = blockIdx.y * 64;
    const int b = blockIdx.z;
    __shared__ unsigned short t[64][72];
    const float* s = src + ((size_t)b * CB + c0) * PP + p0;
    for (int e = threadIdx.x; e < 4096; e += 256) {
        int r = e >> 6, col = e & 63;
        int c = c0 + r;
        float2 m = st[b * 32 + (c >> 3)];       // Cpg = 8
        float a = m.y * sc[c];
        float bb = bi[c] - m.x * a;
        t[r][col] = f2bf(fmaxf(s[(size_t)r * PP + col] * a + bb, 0.f));
    }
    __syncthreads();
    unsigned short* d = dst + ((size_t)b * PP + p0) * CB + c0;
    for (int u = threadIdx.x; u < 512; u += 256) {
        int pr = u >> 3, c8 = (u & 7) * 8;
        ushort4 v0, v1;
        v0.x = t[c8 + 0][pr]; v0.y = t[c8 + 1][pr];
        v0.z = t[c8 + 2][pr]; v0.w = t[c8 + 3][pr];
        v1.x = t[c8 + 4][pr]; v1.y = t[c8 + 5][pr];
        v1.z = t[c8 + 6][pr]; v1.w = t[c8 + 7][pr];
        *(ushort4*)&d[(size_t)pr * CB + c8] = v0;
        *(ushort4*)&d[(size_t)pr * CB + c8 + 4] = v1;
    }
}

// ---------------------------------------------------------------------------
__global__ __launch_bounds__(256)
void cvt_bf16(const float* __restrict__ s, unsigned short* __restrict__ d, int n) {
    int i = blockIdx.x * 256 + threadIdx.x;
    if (i < n) d[i] = f2bf(s[i]);
}

// ---------------------------------------------------------------------------
// Finalize: stats from accumulated partials (one float pair per (b,group)).
// ---------------------------------------------------------------------------
__global__ __launch_bounds__(128)
void gn_stats_fin(const float* __restrict__ pS, const float* __restrict__ pSS,
                  float2* __restrict__ stats, int cnt) {
    int bg = threadIdx.x;           // 128 (b,g) pairs
    float S = pS[bg], SS = pSS[bg];
    float mean = S / (float)cnt;
    float var = SS / (float)cnt - mean * mean;
    stats[bg] = make_float2(mean, rsqrtf(var + EPSV));
}

// ---------------------------------------------------------------------------
// w_off fp32 [27][256][9] -> bf16 wobf [32][2304], layout m*2304 + tap*256 + c,
// rows 27..31 zero (M padded to 32 for MFMA).
// ---------------------------------------------------------------------------
__global__ __launch_bounds__(256)
void woff_conv(const float* __restrict__ w_off, unsigned short* __restrict__ wobf) {
    int t = blockIdx.x * 256 + threadIdx.x;
    if (t >= 32 * 2304) return;
    int m = t / 2304;
    int r = t - m * 2304;
    int tap = r >> 8, c = r & 255;
    float v = (m < 27) ? w_off[((size_t)m * 256 + c) * 9 + tap] : 0.f;
    wobf[t] = f2bf(v);
}

// ---------------------------------------------------------------------------
// Offset conv on MFMA (R17, proven: conv_off 68 -> <15 us).
// ---------------------------------------------------------------------------
__global__ __launch_bounds__(256)
void conv_off_mfma(const unsigned short* __restrict__ bfAT,
                   const unsigned short* __restrict__ wobf,
                   const float* __restrict__ boff,
                   float* __restrict__ om) {
    const int blk = blockIdx.x;          // 512 blocks
    const int xcd = blk & 7;
    const int b = xcd >> 1;              // batch per XCD-pair
    const int tile = ((blk >> 3) << 1) | (xcd & 1);   // 0..127
    const int p0 = tile * 32;
    const int tid = threadIdx.x;
    const int lane = tid & 63;
    const int wid = tid >> 6;            // 0..3
    const int l15 = lane & 15;
    const int quad = lane >> 4;
    const int mh = (wid >> 1) << 4;      // m-half: 0 or 16
    const int ph = (wid & 1) << 4;       // px-half: 0 or 16

    __shared__ __align__(16) unsigned short Bs[8 * 1288];   // 20.6 KB

    const int y0r = p0 >> 6;             // image row (constant per tile)
    const int x0 = p0 & 63;              // 0 or 32
    const unsigned short* xb = bfAT + ((size_t)b << 20);
    const unsigned short* arow = wobf + (size_t)(mh + l15) * 2304 + quad * 8;

    floatx4 acc = (floatx4){0.f, 0.f, 0.f, 0.f};

    for (int tap = 0; tap < 9; ++tap) {
        const int dy = tap / 3 - 1, dx = tap % 3 - 1;
        const int yy = y0r + dy;
        const bool rowok = (yy >= 0 && yy < 64);
        __syncthreads();
        for (int e = tid; e < 1024; e += 256) {
            int px = e >> 5, ck = e & 31;
            int xx = x0 + px + dx;
            uint4 v = make_uint4(0u, 0u, 0u, 0u);
            if (rowok && xx >= 0 && xx < 64) {
                int srow = (yy << 6) + xx;
                v = *(const uint4*)(xb + ((size_t)srow << 8) + ck * 8);
            }
            *(uint4*)((char*)Bs + (ck >> 2) * 2576 + px * 80 + (ck & 3) * 16) = v;
        }
        __syncthreads();
        const unsigned short* at = arow + tap * 256;
#pragma unroll
        for (int cc = 0; cc < 8; ++cc) {
            shortx8 af = *(const shortx8*)(at + cc * 32);
            shortx8 bf = *(const shortx8*)((const char*)Bs + cc * 2576 +
                         (ph + l15) * 80 + quad * 16);
            acc = __builtin_amdgcn_mfma_f32_16x16x32_bf16(af, bf, acc, 0, 0, 0);
        }
    }

    // epilogue: col = l15 (pixel), row = quad*4 + r (within m-half); + bias
#pragma unroll
    for (int r = 0; r < 4; ++r) {
        int m = mh + quad * 4 + r;
        if (m < 27)
            om[((size_t)b * 27 + m) * PP + p0 + ph + l15] = acc[r] + boff[m];
    }
}

// ---------------------------------------------------------------------------
// Deformable einsum, bf16 MFMA. R19: REVERT to the R17 staged-A body
// (proven 58.9 us; R18's direct-A loads regressed to 82.5 — the register
// prefetch window (~1 MFMA phase) can't hide L2 latency, whereas staged A
// gives the load a full segment before its consumer) + keep R18's fused
// GN2-stats epilogue (proven ~20 us pipeline win).
// ---------------------------------------------------------------------------
__global__ __launch_bounds__(512, 2)
void gemm2_mfma(const unsigned short* __restrict__ bfAT,
                const unsigned short* __restrict__ w2bf,
                const float* __restrict__ om, float* __restrict__ out2,
                float* __restrict__ pS, float* __restrict__ pSS) {
    const int blk = blockIdx.x;        // 256 blocks
    const int xcd = blk & 7;
    const int b = xcd >> 1;                          // batch per XCD-pair
    const int p0 = (((blk >> 3) << 1) | (xcd & 1)) * 64;
    const int tid = threadIdx.x;
    const int lane = tid & 63;
    const int wid = tid >> 6;          // 0..7
    const int l15 = lane & 15;
    const int quad = lane >> 4;        // 0..3

    __shared__ __align__(16) unsigned short As0[256 * 40];   // 20 KB
    __shared__ __align__(16) unsigned short As1[256 * 40];   // 20 KB
    __shared__ __align__(16) unsigned short Bs0[64 * 40];    // 5 KB
    __shared__ __align__(16) unsigned short Bs1[64 * 40];    // 5 KB
    __shared__ float sw0[576], sw1[576], sw2[576], sw3[576]; // SoA tables
    __shared__ int   si0[576], si1[576];                     // row indices
    __shared__ float sgs[32], sgss[32];
    if (tid < 32) { sgs[tid] = 0.f; sgss[tid] = 0.f; }

    // sampling tables, 9 taps x 64 pixels
    const float* ob = om + (size_t)b * 27 * PP;
    for (int e = tid; e < 576; e += 512) {
        int k = e >> 6, p = e & 63;
        int pg = p0 + p;
        float offx = ob[(size_t)k * PP + pg];
        float offy = ob[(size_t)(9 + k) * PP + pg];
        float ms = 1.f / (1.f + expf(-ob[(size_t)(18 + k) * PP + pg]));
        int y = pg >> 6, x = pg & 63;
        float py = (float)(y + k / 3 - 1) + offy;
        float px = (float)(x + (k % 3) - 1) + offx;
        float y0f = floorf(py), x0f = floorf(px);
        float wy1 = py - y0f, wx1 = px - x0f;
        int iy0 = (int)y0f, ix0 = (int)x0f;
        int iy1 = iy0 + 1;
        float wy0v = (iy0 >= 0 && iy0 < 64) ? (1.f - wy1) * ms : 0.f;
        float wy1v = (iy1 >= 0 && iy1 < 64) ? wy1 * ms : 0.f;
        int cy0 = min(max(iy0, 0), 63), cy1 = min(max(iy1, 0), 63);
        float xa, xb; int q;
        if (ix0 >= 0 && ix0 <= 62)      { q = ix0; xa = 1.f - wx1; xb = wx1;       }
        else if (ix0 == -1)             { q = 0;   xa = wx1;       xb = 0.f;       }
        else if (ix0 == 63)             { q = 62;  xa = 0.f;       xb = 1.f - wx1; }
        else                            { q = 0;   xa = 0.f;       xb = 0.f;       }
        sw0[e] = wy0v * xa;
        sw1[e] = wy0v * xb;
        sw2[e] = wy1v * xa;
        sw3[e] = wy1v * xb;
        si0[e] = (cy0 << 6) + q;
        si1[e] = (cy1 << 6) + q;
    }

    floatx4 acc[2][4];
#pragma unroll
    for (int i = 0; i < 2; i++)
#pragma unroll
        for (int j = 0; j < 4; j++) acc[i][j] = (floatx4){0.f, 0.f, 0.f, 0.f};

    const int cq = tid & 7;            // channel octet (8 contiguous channels)
    const int bp = tid >> 3;           // pixel within tile 0..63
    const int so = tid >> 1;           // A-stage row 0..255
    const int sh = tid & 1;            // A-stage half (which 32-ch slice)
    const unsigned short* xbase = bfAT + (((size_t)b) << 20);   // b*PP*256
    const unsigned short* abase = w2bf + (size_t)so * 2304 + sh * 32;
    const unsigned short* gbq = xbase + cq * 8;
    const int mbase = wid * 32;

    __syncthreads();   // tables ready (also covers sgs zero-init)

    // ---- prologue: issue loads for segment 0 (cc2=0, tap=0) ----
    float4 a0, a1, a2, a3;
    uint4 v00, v01, v10, v11;
    float w0, w1, w2v, w3v;
    {
        a0 = ((const float4*)abase)[0];
        a1 = ((const float4*)abase)[1];
        a2 = ((const float4*)abase)[2];
        a3 = ((const float4*)abase)[3];
        int tix = bp;
        w0 = sw0[tix]; w1 = sw1[tix]; w2v = sw2[tix]; w3v = sw3[tix];
        int r0 = si0[tix], r1 = si1[tix];
        v00 = *(const uint4*)(gbq + ((size_t)r0 << 8));
        v01 = *(const uint4*)(gbq + ((size_t)(r0 + 1) << 8));
        v10 = *(const uint4*)(gbq + ((size_t)r1 << 8));
        v11 = *(const uint4*)(gbq + ((size_t)(r1 + 1) << 8));
    }

    int tap = 0, cc2 = 0;
    for (int seg = 0; seg < 36; ++seg) {
        // ---- interp current (regs loaded one segment ago) + stage ----
        float f0 = w0 * bflo(v00.x) + w1 * bflo(v01.x)
                 + w2v * bflo(v10.x) + w3v * bflo(v11.x);
        float f1 = w0 * bfhi(v00.x) + w1 * bfhi(v01.x)
                 + w2v * bfhi(v10.x) + w3v * bfhi(v11.x);
        float f2 = w0 * bflo(v00.y) + w1 * bflo(v01.y)
                 + w2v * bflo(v10.y) + w3v * bflo(v11.y);
        float f3 = w0 * bfhi(v00.y) + w1 * bfhi(v01.y)
                 + w2v * bfhi(v10.y) + w3v * bfhi(v11.y);
        float f4 = w0 * bflo(v00.z) + w1 * bflo(v01.z)
                 + w2v * bflo(v10.z) + w3v * bflo(v11.z);
        float f5 = w0 * bfhi(v00.z) + w1 * bfhi(v01.z)
                 + w2v * bfhi(v10.z) + w3v * bfhi(v11.z);
        float f6 = w0 * bflo(v00.w) + w1 * bflo(v01.w)
                 + w2v * bflo(v10.w) + w3v * bflo(v11.w);
        float f7 = w0 * bfhi(v00.w) + w1 * bfhi(v01.w)
                 + w2v * bfhi(v10.w) + w3v * bfhi(v11.w);
        uint4 bw;
        bw.x = (unsigned int)f2bf(f0) | ((unsigned int)f2bf(f1) << 16);
        bw.y = (unsigned int)f2bf(f2) | ((unsigned int)f2bf(f3) << 16);
        bw.z = (unsigned int)f2bf(f4) | ((unsigned int)f2bf(f5) << 16);
        bw.w = (unsigned int)f2bf(f6) | ((unsigned int)f2bf(f7) << 16);
        unsigned short* adst = sh ? As1 : As0;
        *(float4*)((char*)adst + so * 80 +  0) = a0;
        *(float4*)((char*)adst + so * 80 + 16) = a1;
        *(float4*)((char*)adst + so * 80 + 32) = a2;
        *(float4*)((char*)adst + so * 80 + 48) = a3;
        unsigned short* bdst = (cq & 4) ? Bs1 : Bs0;
        *(uint4*)((char*)bdst + bp * 80 + (cq & 3) * 16) = bw;
        __syncthreads();

        // ---- issue next segment's loads (hide under MFMA + barrier) ----
        int ntap = tap + 1, ncc2 = cc2;
        if (ntap == 9) { ntap = 0; ncc2 = (cc2 + 1) & 3; }
        {
            const unsigned short* gsrc = abase + ntap * 256 + ncc2 * 64;
            a0 = ((const float4*)gsrc)[0];
            a1 = ((const float4*)gsrc)[1];
            a2 = ((const float4*)gsrc)[2];
            a3 = ((const float4*)gsrc)[3];
            int tix = ntap * 64 + bp;
            int r0 = si0[tix], r1 = si1[tix];
            const unsigned short* gb = gbq + ncc2 * 64;
            v00 = *(const uint4*)(gb + ((size_t)r0 << 8));
            v01 = *(const uint4*)(gb + ((size_t)(r0 + 1) << 8));
            v10 = *(const uint4*)(gb + ((size_t)r1 << 8));
            v11 = *(const uint4*)(gb + ((size_t)(r1 + 1) << 8));
            w0 = sw0[tix]; w1 = sw1[tix]; w2v = sw2[tix]; w3v = sw3[tix];
        }

        // ---- MFMA on current LDS ----
        shortx8 af[2][2], bfr[2][4];
#pragma unroll
        for (int i = 0; i < 2; i++) {
            af[0][i] = *(const shortx8*)((const char*)As0 +
                       (mbase + 16 * i + l15) * 80 + quad * 16);
            af[1][i] = *(const shortx8*)((const char*)As1 +
                       (mbase + 16 * i + l15) * 80 + quad * 16);
        }
#pragma unroll
        for (int j = 0; j < 4; j++) {
            bfr[0][j] = *(const shortx8*)((const char*)Bs0 +
                        (16 * j + l15) * 80 + quad * 16);
            bfr[1][j] = *(const shortx8*)((const char*)Bs1 +
                        (16 * j + l15) * 80 + quad * 16);
        }
#pragma unroll
        for (int ks = 0; ks < 2; ks++)
#pragma unroll
            for (int i = 0; i < 2; i++)
#pragma unroll
                for (int j = 0; j < 4; j++)
                    acc[i][j] = __builtin_amdgcn_mfma_f32_16x16x32_bf16(
                        af[ks][i], bfr[ks][j], acc[i][j], 0, 0, 0);
        __syncthreads();
        tap = ntap; cc2 = ncc2;
    }

    // epilogue: write C + fused GN2-stats partials
    const size_t chbase = ((size_t)b * CB) << 12;
#pragma unroll
    for (int i = 0; i < 2; i++) {
#pragma unroll
        for (int r = 0; r < 4; r++) {
            int row = mbase + 16 * i + quad * 4 + r;
            float* dst = out2 + chbase + ((size_t)row << 12) + p0 + l15;
            float s = 0.f, ss = 0.f;
#pragma unroll
            for (int j = 0; j < 4; j++) {
                float v = acc[i][j][r];
                dst[16 * j] = v;
                s += v; ss += v * v;
            }
#pragma unroll
            for (int off = 1; off < 16; off <<= 1) {
                s  += __shfl_xor(s, off, 64);
                ss += __shfl_xor(ss, off, 64);
            }
            if (l15 == 0) {
                int g = row >> 3;          // Cpg = 8
                atomicAdd(&sgs[g], s);
                atomicAdd(&sgss[g], ss);
            }
        }
    }
    __syncthreads();
    if (tid < 32) {
        atomicAdd(&pS[b * 32 + tid], sgs[tid]);
        atomicAdd(&pSS[b * 32 + tid], sgss[tid]);
    }
}

// ---------------------------------------------------------------------------
// w2 fp32 [o][c][tap] -> bf16, K reordered: w2bf[o][tap*256 + c]
// ---------------------------------------------------------------------------
__global__ __launch_bounds__(256)
void w2conv(const float* __restrict__ w2, unsigned short* __restrict__ w2bf) {
    int t = blockIdx.x * 256 + threadIdx.x;
    if (t >= 256 * 2304) return;
    int o = t / 2304;
    int r = t - o * 2304;
    int tap = r >> 8, c = r & 255;
    w2bf[t] = f2bf(w2[((size_t)o * 256 + c) * 9 + tap]);
}

// ---------------------------------------------------------------------------
// Final: relu(gn3(d_out)*sc+bi + x) in place.
// ---------------------------------------------------------------------------
__global__ __launch_bounds__(256)
void final_k(float* __restrict__ dout, const float* __restrict__ x,
             const float2* __restrict__ stats, const float* __restrict__ sc,
             const float* __restrict__ bi) {
    long i = (long)blockIdx.x * 256 + threadIdx.x;
    long total4 = ((long)BATCH * CIN * PP) >> 2;
    if (i >= total4) return;
    long e = i << 2;
    int c = (int)((e >> 12) & 1023);
    int b = (int)(e >> 22);
    float2 st = stats[b * 32 + (c >> 5)];
    float a = st.y * sc[c];
    float bb = bi[c] - st.x * a;
    float4 v = ((float4*)dout)[i];
    float4 xv = ((const float4*)x)[i];
    v.x = fmaxf(v.x * a + bb + xv.x, 0.f);
    v.y = fmaxf(v.y * a + bb + xv.y, 0.f);
    v.z = fmaxf(v.z * a + bb + xv.z, 0.f);
    v.w = fmaxf(v.w * a + bb + xv.w, 0.f);
    ((float4*)dout)[i] = v;
}

// ---------------------------------------------------------------------------
// Workspace: bfAT at ws+6422528; wobf at ws+9256960; stats partials (pbuf,
// 768 floats, memset to 0) after st3.
// ---------------------------------------------------------------------------
extern "C" void kernel_launch(void* const* d_in, const int* in_sizes, int n_in,
                              void* d_out, int out_size, void* d_ws, size_t ws_size,
                              hipStream_t stream) {
    const float* x   = (const float*)d_in[0];
    const float* w1  = (const float*)d_in[1];
    const float* g1s = (const float*)d_in[2];
    const float* g1b = (const float*)d_in[3];
    const float* wof = (const float*)d_in[4];
    const float* bof = (const float*)d_in[5];
    const float* w2  = (const float*)d_in[6];
    const float* g2s = (const float*)d_in[7];
    const float* g2b = (const float*)d_in[8];
    const float* w3  = (const float*)d_in[9];
    const float* g3s = (const float*)d_in[10];
    const float* g3b = (const float*)d_in[11];
    float* out = (float*)d_out;

    float* ws = (float*)d_ws;
    unsigned short* w1bf   = (unsigned short*)(ws + 0);
    float*          out1r  = ws + 131072;               // conv1 raw out
    float*          out2   = ws + 131072;               // aliases out1r (dead)
    unsigned short* xbfT   = (unsigned short*)(ws + 4325376);
    unsigned short* bfAT   = (unsigned short*)(ws + 6422528);  // pixel-major GN1 out
    float*          om     = ws + 8519680;
    unsigned short* w2bf   = (unsigned short*)(ws + 8962048);
    unsigned short* wobf   = (unsigned short*)(ws + 9256960);  // offset-conv W bf16
    unsigned short* out2bT = (unsigned short*)(ws + 4325376);  // reuses xbfT region
    unsigned short* w3bf   = (unsigned short*)(ws + 11354112);
    float2* st1  = (float2*)(ws + 11485184);
    float2* st2  = st1 + 128;
    float2* st3  = st2 + 128;
    float*  pbuf = ws + 11485184 + 768;   // 768 floats: 3 stages x (S[128],SS[128])
    float*  p1S = pbuf,       *p1SS = pbuf + 128;
    float*  p2S = pbuf + 256, *p2SS = pbuf + 384;
    float*  p3S = pbuf + 512, *p3SS = pbuf + 640;

    hipMemsetAsync(pbuf, 0, 768 * sizeof(float), stream);

    // x [b][1024][4096] -> xbfT [b][4096][1024] bf16
    transp_bf16<<<dim3(64, 16, 4), 256, 0, stream>>>(x, xbfT, 1024, 4096);
    cvt_bf16<<<1024, 256, 0, stream>>>(w1, w1bf, 262144);
    // conv1 (+fused GN1 stats partials): out1r = w1bf @ xbfT
    gemm_bf16<<<dim3(32, 2, 4), 256, 0, stream>>>(w1bf, xbfT, out1r, 256, 4096, 1024,
                                                  p1S, p1SS, 3);
    gn_stats_fin<<<1, 128, 0, stream>>>(p1S, p1SS, st1, 8 * PP);
    // GN1 apply + ReLU -> bfAT (pixel-major)
    gn2t<<<dim3(64, 4, 4), 256, 0, stream>>>(out1r, st1, g1s, g1b, bfAT);
    // offset conv on MFMA (reads bfAT; bias fused)
    woff_conv<<<288, 256, 0, stream>>>(wof, wobf);
    conv_off_mfma<<<512, 256, 0, stream>>>(bfAT, wobf, bof, om);
    // weight conversions
    w2conv<<<2304, 256, 0, stream>>>(w2, w2bf);
    cvt_bf16<<<1024, 256, 0, stream>>>(w3, w3bf, 262144);
    // deformable einsum (+fused GN2 stats partials) -> out2
    gemm2_mfma<<<dim3(256, 1, 1), 512, 0, stream>>>(bfAT, w2bf, om, out2, p2S, p2SS);
    gn_stats_fin<<<1, 128, 0, stream>>>(p2S, p2SS, st2, 8 * PP);
    gn2t<<<dim3(64, 4, 4), 256, 0, stream>>>(out2, st2, g2s, g2b, out2bT);
    // conv3 (+fused GN3 stats partials): out = w3bf @ out2bT
    gemm_bf16<<<dim3(32, 8, 4), 256, 0, stream>>>(w3bf, out2bT, out, 1024, 4096, 256,
                                                  p3S, p3SS, 5);
    gn_stats_fin<<<1, 128, 0, stream>>>(p3S, p3SS, st3, 32 * PP);
    final_k<<<16384, 256, 0, stream>>>(out, x, st3, g3s, g3b);
}